// Round 1
// baseline (517.929 us; speedup 1.0000x reference)
//
#include <hip/hip_runtime.h>

// Lattice: 32^4 sites, F=8 channels, complex 3-vectors, 4 link directions.
// x:  (8, 32,32,32,32, 3)  complex (split re/im arrays)
// U:  (4, 32,32,32,32, 3,3) complex (split re/im arrays)
// out: (2, 8, 32,32,32,32, 3) float32  [re block then im block]

#define L 32
#define V (32*32*32*32)          // 1,048,576 sites
#define V3 (V*3)
#define SX (32*32*32)            // +1 in x  -> +32768 sites
#define SY (32*32)               // +1 in y  -> +1024
#define SZ 32                    // +1 in z  -> +32
// t stride = 1

__device__ __forceinline__ void load_vec(const float* __restrict__ xr,
                                         const float* __restrict__ xi,
                                         int f, int s, float vr[3], float vi[3]) {
    long b = (long)f * V3 + (long)s * 3;
    vr[0] = xr[b+0]; vr[1] = xr[b+1]; vr[2] = xr[b+2];
    vi[0] = xi[b+0]; vi[1] = xi[b+1]; vi[2] = xi[b+2];
}

__device__ __forceinline__ void load_U(const float* __restrict__ Ur_g,
                                       const float* __restrict__ Ui_g,
                                       int mu, int s, float Ur[9], float Ui[9]) {
    long b = (long)mu * (long)V * 9 + (long)s * 9;
#pragma unroll
    for (int k = 0; k < 9; ++k) { Ur[k] = Ur_g[b+k]; Ui[k] = Ui_g[b+k]; }
}

// y = U v   (complex 3x3 times complex 3-vector)
__device__ __forceinline__ void matvec(const float Ur[9], const float Ui[9],
                                       const float vr[3], const float vi[3],
                                       float yr[3], float yi[3]) {
#pragma unroll
    for (int a = 0; a < 3; ++a) {
        float ar = 0.f, ai = 0.f;
#pragma unroll
        for (int b = 0; b < 3; ++b) {
            float ur = Ur[a*3+b], ui = Ui[a*3+b];
            ar += ur * vr[b] - ui * vi[b];
            ai += ur * vi[b] + ui * vr[b];
        }
        yr[a] = ar; yi[a] = ai;
    }
}

// y = U^dag v  (conjugate transpose)
__device__ __forceinline__ void matvec_dag(const float Ur[9], const float Ui[9],
                                           const float vr[3], const float vi[3],
                                           float yr[3], float yi[3]) {
#pragma unroll
    for (int a = 0; a < 3; ++a) {
        float ar = 0.f, ai = 0.f;
#pragma unroll
        for (int b = 0; b < 3; ++b) {
            float ur = Ur[b*3+a], ui = Ui[b*3+a];   // transpose
            ar += ur * vr[b] + ui * vi[b];          // conj: +ui*vi
            ai += ur * vi[b] - ui * vr[b];          // conj: -ui*vr
        }
        yr[a] = ar; yi[a] = ai;
    }
}

__device__ __forceinline__ void store_out(float* __restrict__ outr,
                                          float* __restrict__ outi,
                                          int f, int s, float sc,
                                          const float yr[3], const float yi[3]) {
    long b = (long)f * V3 + (long)s * 3;
    outr[b+0] = sc*yr[0]; outr[b+1] = sc*yr[1]; outr[b+2] = sc*yr[2];
    outi[b+0] = sc*yi[0]; outi[b+1] = sc*yi[1]; outi[b+2] = sc*yi[2];
}

__global__ void transport_kernel(const float* __restrict__ xr,
                                 const float* __restrict__ xi,
                                 const float* __restrict__ Urg,
                                 const float* __restrict__ Uig,
                                 float* __restrict__ outr,
                                 float* __restrict__ outi) {
    int s = blockIdx.x * blockDim.x + threadIdx.x;
    if (s >= V) return;

    int t = s & 31;
    int z = (s >> 5) & 31;
    int y = (s >> 10) & 31;
    int x = (s >> 15) & 31;

    int s_xp = s + ((x == 31) ? -(31*SX) : SX);
    int s_xm = s + ((x == 0)  ?  (31*SX) : -SX);
    int s_yp = s + ((y == 31) ? -(31*SY) : SY);
    int s_ym = s + ((y == 0)  ?  (31*SY) : -SY);
    int s_zp = s + ((z == 31) ? -(31*SZ) : SZ);
    int s_tp = s + ((t == 31) ? -31 : 1);
    int s_xpyp = s_yp + ((x == 31) ? -(31*SX) : SX);

    float eta1 = (x & 1) ? -1.f : 1.f;            // (-1)^x0
    float eta2 = ((x + y) & 1) ? -1.f : 1.f;      // (-1)^(x0+x1)
    float eta3 = ((x + y + z) & 1) ? -1.f : 1.f;  // (-1)^(x0+x1+x2)

    float vr[3], vi[3], yr[3], yi[3], Ur[9], Ui[9];

    // ch0: identity
    load_vec(xr, xi, 0, s, vr, vi);
    store_out(outr, outi, 0, s, 1.f, vr, vi);

    // ch1: (0,+1): U0(x) x1(x+xhat), eta0 = 1
    load_U(Urg, Uig, 0, s, Ur, Ui);
    load_vec(xr, xi, 1, s_xp, vr, vi);
    matvec(Ur, Ui, vr, vi, yr, yi);
    store_out(outr, outi, 1, s, 1.f, yr, yi);

    // ch7 first part needs U1(s); do ch2 now while U1 loaded later.
    // ch2: (1,+1): eta1(x) U1(x) x2(x+yhat)
    load_U(Urg, Uig, 1, s, Ur, Ui);
    load_vec(xr, xi, 2, s_yp, vr, vi);
    matvec(Ur, Ui, vr, vi, yr, yi);
    store_out(outr, outi, 2, s, eta1, yr, yi);

    // ch7: (0,+1) then (1,+1): eta1(x) * U1(x) @ U0(x+yhat) @ x7(x+xhat+yhat)
    // U1(s) is currently in Ur/Ui -- compute inner product first with U0(s_yp).
    {
        float U1r[9], U1i[9];
#pragma unroll
        for (int k = 0; k < 9; ++k) { U1r[k] = Ur[k]; U1i[k] = Ui[k]; }
        load_U(Urg, Uig, 0, s_yp, Ur, Ui);
        load_vec(xr, xi, 7, s_xpyp, vr, vi);
        float gr[3], gi[3];
        matvec(Ur, Ui, vr, vi, gr, gi);           // g = U0(x+yhat) x7(...)
        matvec(U1r, U1i, gr, gi, yr, yi);         // y = U1(x) g
        store_out(outr, outi, 7, s, eta1, yr, yi);
    }

    // ch3: (2,+1): eta2(x) U2(x) x3(x+zhat)
    load_U(Urg, Uig, 2, s, Ur, Ui);
    load_vec(xr, xi, 3, s_zp, vr, vi);
    matvec(Ur, Ui, vr, vi, yr, yi);
    store_out(outr, outi, 3, s, eta2, yr, yi);

    // ch4: (3,+1): eta3(x) U3(x) x4(x+that)
    load_U(Urg, Uig, 3, s, Ur, Ui);
    load_vec(xr, xi, 4, s_tp, vr, vi);
    matvec(Ur, Ui, vr, vi, yr, yi);
    store_out(outr, outi, 4, s, eta3, yr, yi);

    // ch5: (0,-1): eta0 = 1; U0^dag(x-xhat) x5(x-xhat)
    load_U(Urg, Uig, 0, s_xm, Ur, Ui);
    load_vec(xr, xi, 5, s_xm, vr, vi);
    matvec_dag(Ur, Ui, vr, vi, yr, yi);
    store_out(outr, outi, 5, s, 1.f, yr, yi);

    // ch6: (1,-1): eta1(x-yhat) = eta1(x) (depends only on x0); U1^dag(x-yhat) x6(x-yhat)
    load_U(Urg, Uig, 1, s_ym, Ur, Ui);
    load_vec(xr, xi, 6, s_ym, vr, vi);
    matvec_dag(Ur, Ui, vr, vi, yr, yi);
    store_out(outr, outi, 6, s, eta1, yr, yi);
}

extern "C" void kernel_launch(void* const* d_in, const int* in_sizes, int n_in,
                              void* d_out, int out_size, void* d_ws, size_t ws_size,
                              hipStream_t stream) {
    const float* xr  = (const float*)d_in[0];
    const float* xi  = (const float*)d_in[1];
    const float* Urg = (const float*)d_in[2];
    const float* Uig = (const float*)d_in[3];
    float* outr = (float*)d_out;
    float* outi = (float*)d_out + (long)8 * V3;   // imag block after real block

    const int block = 256;
    const int grid = V / block;                   // 4096 blocks
    transport_kernel<<<grid, block, 0, stream>>>(xr, xi, Urg, Uig, outr, outi);
}